// Round 13
// baseline (2935.037 us; speedup 1.0000x reference)
//
#include <hip/hip_runtime.h>
#include <math.h>

#define TPB 256

static __device__ __forceinline__ float4 mk4(float a, float b, float c, float d) {
  float4 r; r.x = a; r.y = b; r.z = c; r.w = d; return r;
}

// Swizzled LDS helpers for [64][64] f32 tiles: 16B chunk c of row r lives at
// chunk c ^ (r>>2).  Bank-conflict-free for row-broadcast + row-striped reads.
static __device__ __forceinline__ float4 ld4s(const float* buf, int row, int ch) {
  return *(const float4*)&buf[(row << 6) + (((ch ^ (row >> 2)) & 15) << 2)];
}
static __device__ __forceinline__ void st4s(float* buf, int row, int ch, float4 v) {
  *(float4*)&buf[(row << 6) + (((ch ^ (row >> 2)) & 15) << 2)] = v;
}

// ---------------------------------------------------------------------------
// RoPE cos/sin tables, replicating JAX f32 arithmetic exactly. (unchanged)
// ---------------------------------------------------------------------------
__global__ __launch_bounds__(TPB) void k_tables(float* __restrict__ cosb,
                                                float* __restrict__ sinb) {
  int gid = blockIdx.x * TPB + threadIdx.x;
  if (gid >= 1024 * 32) return;
  int t = gid >> 5, j = gid & 31;
  const double Ld = 1.3222192947339193;  // python math.log10(21.0)
  float Lf = (float)Ld;
  float mlog;
  if (j == 31) {
    mlog = Lf;
  } else {
    float stepf = (float)((double)j / 31.0);
    mlog = (float)((double)Lf * (double)stepf);
  }
  float p = (float)pow(10.0, (double)mlog);
  float mel = p - 1.0f;
  float t2 = (200.0f * mel) / 1000.0f;
  float freq = 163.63636363636363f * t2;
  float ang = (float)t * freq;
  double a = (double)ang;
  cosb[gid] = (float)cos(a);
  sinb[gid] = (float)sin(a);
}

// ---------------------------------------------------------------------------
// Per-row 1/rms over D=1024 (unchanged)
// ---------------------------------------------------------------------------
__global__ __launch_bounds__(TPB) void k_rowinv(const float* __restrict__ X,
                                                float* __restrict__ inv) {
  __shared__ float red[4];
  int row = blockIdx.x;
  int tid = threadIdx.x;
  float4 v = *(const float4*)(X + (size_t)row * 1024 + tid * 4);
  float ss = v.x * v.x + v.y * v.y + v.z * v.z + v.w * v.w;
#pragma unroll
  for (int m = 1; m < 64; m <<= 1) ss += __shfl_xor(ss, m);
  if ((tid & 63) == 0) red[tid >> 6] = ss;
  __syncthreads();
  if (tid == 0) {
    float s = ((red[0] + red[1]) + (red[2] + red[3]));
    float mm = s * (1.0f / 1024.0f) + 1.1920928955078125e-7f;
    inv[row] = (float)(1.0 / sqrt((double)mm));
  }
}

// ---------------------------------------------------------------------------
// Tiled f32 GEMM v4: BMxBN block, BK=32, DOUBLE-BUFFERED A tile with ONE
// barrier per K-step (write buf[p] -> barrier -> compute buf[p]; safe with
// 2 buffers since compute(i-2) precedes barrier(i-1) precedes write(i)).
// Barriers per block: 32 (was 128 at BK=16 x 2 barriers).  A-panel register
// prefetch hides global latency under compute.  B direct from global.
// Per-output k-chain visits k=0..1023 strictly ascending — accumulation
// order identical to all prior rounds (absmax must stay 1.373291e-4).
// ---------------------------------------------------------------------------
template <int BM, int BN>
__global__ __launch_bounds__(TPB) void k_gemm(
    const float* __restrict__ X, const float* __restrict__ inv,
    const float* __restrict__ wn, const float* __restrict__ W,
    const float* __restrict__ bias, float* __restrict__ o0,
    float* __restrict__ o1, int N, int mode) {
  constexpr int JW = BN / 64;    // col halves (1 or 2)
  constexpr int RH = BM / 64;    // row halves (1 or 2)
  constexpr int TPR = 256 / BM;  // threads staging one A row
  constexpr int F4PT = BM / 32;  // float4 stages per thread (BK=32)
  __shared__ float As[2][32][BM + 4];
  int tid = threadIdx.x;
  int bx = blockIdx.x, by = blockIdx.y;
  int tx = tid & 15, ty = tid >> 4;
  float c[4 * RH][4 * JW];
#pragma unroll
  for (int i = 0; i < 4 * RH; ++i)
#pragma unroll
    for (int j = 0; j < 4 * JW; ++j) c[i][j] = 0.0f;

  int arow = tid / TPR;
  int kqb[F4PT];
#pragma unroll
  for (int u = 0; u < F4PT; ++u) kqb[u] = ((tid % TPR) * F4PT + u) * 4;
  float sA = 1.0f;
  if (inv) sA = inv[by * BM + arow];
  const float* Xrow = X + (size_t)(by * BM + arow) * 1024;
  const float* Wb = W + bx * BN + tx * 4;

  float4 areg[F4PT];
#pragma unroll
  for (int u = 0; u < F4PT; ++u)
    areg[u] = *(const float4*)(Xrow + kqb[u]);

  int p = 0;
  for (int k0 = 0; k0 < 1024; k0 += 32) {
    // ---- scale + store prefetched A regs to LDS buffer p
#pragma unroll
    for (int u = 0; u < F4PT; ++u) {
      int kq = kqb[u];
      float4 a4 = areg[u];
      if (wn) {
        float4 w4 = *(const float4*)(wn + k0 + kq);
        a4.x *= w4.x; a4.y *= w4.y; a4.z *= w4.z; a4.w *= w4.w;
      }
      a4.x *= sA; a4.y *= sA; a4.z *= sA; a4.w *= sA;
      As[p][kq + 0][arow] = a4.x;
      As[p][kq + 1][arow] = a4.y;
      As[p][kq + 2][arow] = a4.z;
      As[p][kq + 3][arow] = a4.w;
    }
    __syncthreads();  // single barrier per step (double-buffered)
    // ---- issue next-panel A loads (latency hidden under compute)
    if (k0 + 32 < 1024) {
#pragma unroll
      for (int u = 0; u < F4PT; ++u)
        areg[u] = *(const float4*)(Xrow + k0 + 32 + kqb[u]);
    }
    // ---- compute 32 kk steps from buffer p
#pragma unroll 8
    for (int kk = 0; kk < 32; ++kk) {
      float av[4 * RH];
      float4 a0 = *(const float4*)&As[p][kk][ty * 4];
      av[0] = a0.x; av[1] = a0.y; av[2] = a0.z; av[3] = a0.w;
      if (RH == 2) {
        float4 a1 = *(const float4*)&As[p][kk][64 + ty * 4];
        av[4] = a1.x; av[5] = a1.y; av[6] = a1.z; av[7] = a1.w;
      }
      const float* wrow = Wb + (size_t)(k0 + kk) * N;
      float4 b0 = *(const float4*)(wrow);
      float bv[4 * JW];
      bv[0] = b0.x; bv[1] = b0.y; bv[2] = b0.z; bv[3] = b0.w;
      if (JW == 2) {
        float4 b1 = *(const float4*)(wrow + 64);
        bv[4] = b1.x; bv[5] = b1.y; bv[6] = b1.z; bv[7] = b1.w;
      }
#pragma unroll
      for (int i = 0; i < 4 * RH; ++i)
#pragma unroll
        for (int j = 0; j < 4 * JW; ++j) c[i][j] += av[i] * bv[j];
    }
    p ^= 1;
  }

#pragma unroll
  for (int jh = 0; jh < JW; ++jh) {
    int colbase = bx * BN + jh * 64 + tx * 4;
    float4 bb = {0.f, 0.f, 0.f, 0.f};
    if (bias) bb = *(const float4*)(bias + colbase);
#pragma unroll
    for (int ih = 0; ih < RH; ++ih) {
#pragma unroll
      for (int i2 = 0; i2 < 4; ++i2) {
        int row = by * BM + ih * 64 + ty * 4 + i2;
        int ci = ih * 4 + i2;
        float4 o;
        o.x = c[ci][jh * 4 + 0] + bb.x;
        o.y = c[ci][jh * 4 + 1] + bb.y;
        o.z = c[ci][jh * 4 + 2] + bb.z;
        o.w = c[ci][jh * 4 + 3] + bb.w;
        if (mode == 0) {
          *(float4*)(o0 + (size_t)row * N + colbase) = o;
        } else {
          int b = row >> 10, t = row & 1023;
          float* dst = o0;
          int cc = colbase;
          if (mode == 2 && colbase >= 1024) { dst = o1; cc = colbase - 1024; }
          int ch = cc >> 6, d = cc & 63;
          *(float4*)(dst + ((size_t)((b * 16 + ch) * 1024 + t)) * 64 + d) = o;
        }
      }
    }
  }
}

// ---------------------------------------------------------------------------
// In-place RoPE (final focus only)
// ---------------------------------------------------------------------------
__global__ __launch_bounds__(TPB) void k_rope(float* __restrict__ A, int mask,
                                              const float* __restrict__ cosb,
                                              const float* __restrict__ sinb) {
  int gid = blockIdx.x * TPB + threadIdx.x;
  int j = gid & 31;
  int row = gid >> 5;
  int t = row & 1023;
  int aidx = ((t & mask) << 5) + j;
  float cc = cosb[aidx], sn = sinb[aidx];
  size_t base = (size_t)row * 64;
  float x1 = A[base + 2 * j], x2 = A[base + 2 * j + 1];
  A[base + 2 * j] = x1 * cc - x2 * sn;
  A[base + 2 * j + 1] = x1 * sn + x2 * cc;
}

// ---------------------------------------------------------------------------
// Projections for the FINAL focus (CQ=1024): qph (rms-normed, row-major),
// kc <- raw kp, kphT (rms-normed, TRANSPOSED [bh][d][t]), vc <- vp.
// ---------------------------------------------------------------------------
__global__ __launch_bounds__(TPB) void k_proj(
    const float* __restrict__ curq, float* __restrict__ kc,
    float* __restrict__ vc, float* __restrict__ qph, float* __restrict__ kphT,
    const float* __restrict__ Wlq, const float* __restrict__ blq,
    const float* __restrict__ Wlk, const float* __restrict__ blk,
    const float* __restrict__ Wlv, const float* __restrict__ blv,
    const float* __restrict__ wln, int CQ, const int* __restrict__ flags) {
  int RT = CQ >> 4;
  int bid = blockIdx.x;
  int rt = bid % RT;
  int rest = bid / RT;
  int h = rest & 15; rest >>= 4;
  int b = rest & 3;
  int win = rest >> 2;
  if (flags && flags[win]) return;
  __shared__ float qs[16][68], ksm[16][68], vsm[16][68];
  __shared__ float Wqs[4096], Wks[4096], Wvs[4096];
  int tid = threadIdx.x;
#pragma unroll
  for (int i = 0; i < 4; ++i) {
    int f4 = (i * 256 + tid) * 4;
    *(float4*)&Wqs[f4] = *(const float4*)(Wlq + f4);
    *(float4*)&Wks[f4] = *(const float4*)(Wlk + f4);
    *(float4*)&Wvs[f4] = *(const float4*)(Wlv + f4);
  }
  int lr = tid >> 4, c4 = (tid & 15) * 4;
  int bh = b * 16 + h;
  size_t rowbase = (size_t)bh * 1024 + (size_t)win * CQ + rt * 16;
  size_t g = (rowbase + lr) * 64 + c4;
  *(float4*)&qs[lr][c4] = *(const float4*)(curq + g);
  *(float4*)&ksm[lr][c4] = *(const float4*)(kc + g);
  *(float4*)&vsm[lr][c4] = *(const float4*)(vc + g);
  __syncthreads();
  int r = tid >> 4, cg = tid & 15;
  int tglob = win * CQ + rt * 16 + r;
  const float eps = 1.1920928955078125e-7f;
  float4 wl4 = *(const float4*)(wln + cg * 4);
  size_t orow = (rowbase + r) * 64 + cg * 4;
  float4 acc;
  float ssum, rms;
  // ---- Q
  acc = *(const float4*)(blq + cg * 4);
#pragma unroll 8
  for (int k = 0; k < 64; ++k) {
    float xv = qs[r][k];
    float4 w4 = *(const float4*)&Wqs[k * 64 + cg * 4];
    acc.x += xv * w4.x; acc.y += xv * w4.y;
    acc.z += xv * w4.z; acc.w += xv * w4.w;
  }
  ssum = acc.x * acc.x + acc.y * acc.y + acc.z * acc.z + acc.w * acc.w;
#pragma unroll
  for (int m = 1; m < 16; m <<= 1) ssum += __shfl_xor(ssum, m);
  rms = (float)(1.0 / sqrt((double)(ssum * 0.015625f + eps)));
  {
    float4 o;
    o.x = acc.x * rms * wl4.x; o.y = acc.y * rms * wl4.y;
    o.z = acc.z * rms * wl4.z; o.w = acc.w * rms * wl4.w;
    *(float4*)(qph + orow) = o;
  }
  // ---- K
  acc = *(const float4*)(blk + cg * 4);
#pragma unroll 8
  for (int k = 0; k < 64; ++k) {
    float xv = ksm[r][k];
    float4 w4 = *(const float4*)&Wks[k * 64 + cg * 4];
    acc.x += xv * w4.x; acc.y += xv * w4.y;
    acc.z += xv * w4.z; acc.w += xv * w4.w;
  }
  *(float4*)(kc + orow) = acc;  // raw kp -> next kc
  ssum = acc.x * acc.x + acc.y * acc.y + acc.z * acc.z + acc.w * acc.w;
#pragma unroll
  for (int m = 1; m < 16; m <<= 1) ssum += __shfl_xor(ssum, m);
  rms = (float)(1.0 / sqrt((double)(ssum * 0.015625f + eps)));
  {
    float no0 = acc.x * rms * wl4.x;
    float no1 = acc.y * rms * wl4.y;
    float no2 = acc.z * rms * wl4.z;
    float no3 = acc.w * rms * wl4.w;
    size_t tb = (size_t)bh * 64 + cg * 4;
    kphT[(tb + 0) * 1024 + tglob] = no0;
    kphT[(tb + 1) * 1024 + tglob] = no1;
    kphT[(tb + 2) * 1024 + tglob] = no2;
    kphT[(tb + 3) * 1024 + tglob] = no3;
  }
  // ---- V
  acc = *(const float4*)(blv + cg * 4);
#pragma unroll 8
  for (int k = 0; k < 64; ++k) {
    float xv = vsm[r][k];
    float4 w4 = *(const float4*)&Wvs[k * 64 + cg * 4];
    acc.x += xv * w4.x; acc.y += xv * w4.y;
    acc.z += xv * w4.z; acc.w += xv * w4.w;
  }
  *(float4*)(vc + orow) = acc;
}

// ---------------------------------------------------------------------------
// Per-thread 4-row proj for the fused slide kernel (unchanged)
// ---------------------------------------------------------------------------
static __device__ __forceinline__ void slide_proj_one(
    float* src, float* rawdst, float* ndst, const float* __restrict__ W,
    const float* __restrict__ bias, float4 wl4, int tx, int ty) {
  const float eps = 1.1920928955078125e-7f;
  float4 bb = *(const float4*)(bias + tx * 4);
  float4 acc[4];
#pragma unroll
  for (int i = 0; i < 4; ++i) acc[i] = bb;
#pragma unroll 2
  for (int k4 = 0; k4 < 16; ++k4) {
    const float* w = W + (k4 * 4) * 64 + tx * 4;
    float4 w0 = *(const float4*)(w);
    float4 w1 = *(const float4*)(w + 64);
    float4 w2 = *(const float4*)(w + 128);
    float4 w3 = *(const float4*)(w + 192);
#pragma unroll
    for (int i = 0; i < 4; ++i) {
      float4 a4 = ld4s(src, ty * 4 + i, k4);
      acc[i].x += a4.x * w0.x; acc[i].y += a4.x * w0.y;
      acc[i].z += a4.x * w0.z; acc[i].w += a4.x * w0.w;
      acc[i].x += a4.y * w1.x; acc[i].y += a4.y * w1.y;
      acc[i].z += a4.y * w1.z; acc[i].w += a4.y * w1.w;
      acc[i].x += a4.z * w2.x; acc[i].y += a4.z * w2.y;
      acc[i].z += a4.z * w2.z; acc[i].w += a4.z * w2.w;
      acc[i].x += a4.w * w3.x; acc[i].y += a4.w * w3.y;
      acc[i].z += a4.w * w3.z; acc[i].w += a4.w * w3.w;
    }
  }
#pragma unroll
  for (int i = 0; i < 4; ++i) {
    int row = ty * 4 + i;
    if (rawdst) st4s(rawdst, row, tx, acc[i]);
    if (ndst) {
      float ssum = acc[i].x * acc[i].x + acc[i].y * acc[i].y +
                   acc[i].z * acc[i].z + acc[i].w * acc[i].w;
#pragma unroll
      for (int mm = 1; mm < 16; mm <<= 1) ssum += __shfl_xor(ssum, mm);
      float rms = (float)(1.0 / sqrt((double)(ssum * 0.015625f + eps)));
      st4s(ndst, row, tx, mk4(acc[i].x * rms * wl4.x, acc[i].y * rms * wl4.y,
                              acc[i].z * rms * wl4.z, acc[i].w * rms * wl4.w));
    }
  }
}

// ---------------------------------------------------------------------------
// Fused slide-window focus (unchanged from round 5)
// ---------------------------------------------------------------------------
__global__ __launch_bounds__(TPB) void k_slide(
    const float* __restrict__ Qg, const float* __restrict__ Kg,
    const float* __restrict__ Vg, float* __restrict__ curqg,
    float* __restrict__ kcg, float* __restrict__ vcg, float* __restrict__ outb,
    float* __restrict__ diffp, const int* __restrict__ flags,
    const float* __restrict__ cosb, const float* __restrict__ sinb,
    const float* __restrict__ Wlq, const float* __restrict__ blq,
    const float* __restrict__ Wlk, const float* __restrict__ blk,
    const float* __restrict__ Wlv, const float* __restrict__ blv,
    const float* __restrict__ wln, int mode) {
  int bid = blockIdx.x;
  int win = bid & 15, bh = bid >> 4;
  int h = bh & 15, b = bh >> 4;
  if (mode == 2 && flags[win]) return;
  __shared__ float sX[4096], sKc[4096], sVc[4096], sQp[4096], sKp[4096];
  int tid = threadIdx.x;
  int tx = tid & 15, ty = tid >> 4;
  size_t bh1024 = (size_t)bh * 1024;
  int t0 = win * 64;
  const float SCL = 0.18033688011112042f;  // log2(e)/8

  if (mode == 0) {
    int sw = (win == 0) ? 0 : win * 64 - 4;
#pragma unroll
    for (int u = 0; u < 4; ++u) {
      int f4 = u * 256 + tid;
      int row = f4 >> 4, ch = f4 & 15;
      int aidx = (row << 5) + ch * 2;
      float c0 = cosb[aidx], s0 = sinb[aidx];
      float c1 = cosb[aidx + 1], s1 = sinb[aidx + 1];
      float4 q = *(const float4*)(Qg + (bh1024 + t0 + row) * 64 + ch * 4);
      st4s(sX, row, ch, mk4(q.x * c0 - q.y * s0, q.x * s0 + q.y * c0,
                            q.z * c1 - q.w * s1, q.z * s1 + q.w * c1));
      float4 k = *(const float4*)(Kg + (bh1024 + sw + row) * 64 + ch * 4);
      st4s(sKc, row, ch, mk4(k.x * c0 - k.y * s0, k.x * s0 + k.y * c0,
                             k.z * c1 - k.w * s1, k.z * s1 + k.w * c1));
      st4s(sVc, row, ch,
           *(const float4*)(Vg + (bh1024 + sw + row) * 64 + ch * 4));
    }
  } else {
#pragma unroll
    for (int u = 0; u < 4; ++u) {
      int f4 = u * 256 + tid;
      int row = f4 >> 4, ch = f4 & 15;
      size_t g = (bh1024 + t0 + row) * 64 + ch * 4;
      st4s(sX, row, ch, *(const float4*)(curqg + g));
      st4s(sKc, row, ch, *(const float4*)(kcg + g));
      st4s(sVc, row, ch, *(const float4*)(vcg + g));
    }
  }
  float4 wl4 = *(const float4*)(wln + tx * 4);
  float4 prev4[4];
  int niter = (mode == 0) ? 2 : 1;
  for (int it = 0; it < niter; ++it) {
    __syncthreads();
    slide_proj_one(sX, nullptr, sQp, Wlq, blq, wl4, tx, ty);
    slide_proj_one(sKc, sKc, sKp, Wlk, blk, wl4, tx, ty);
    slide_proj_one(sVc, sVc, nullptr, Wlv, blv, wl4, tx, ty);
    __syncthreads();
    float s4[4][4];
#pragma unroll
    for (int i = 0; i < 4; ++i)
      s4[i][0] = s4[i][1] = s4[i][2] = s4[i][3] = 0.0f;
#pragma unroll 4
    for (int d4 = 0; d4 < 16; ++d4) {
      float4 kv[4];
#pragma unroll
      for (int j = 0; j < 4; ++j) kv[j] = ld4s(sKp, tx * 4 + j, d4);
#pragma unroll
      for (int i = 0; i < 4; ++i) {
        float4 q4 = ld4s(sQp, ty * 4 + i, d4);
#pragma unroll
        for (int j = 0; j < 4; ++j) {
          s4[i][j] += q4.x * kv[j].x;
          s4[i][j] += q4.y * kv[j].y;
          s4[i][j] += q4.z * kv[j].z;
          s4[i][j] += q4.w * kv[j].w;
        }
      }
    }
    float lrow[4];
#pragma unroll
    for (int i = 0; i < 4; ++i) {
      s4[i][0] *= SCL; s4[i][1] *= SCL; s4[i][2] *= SCL; s4[i][3] *= SCL;
      float r0 = fmaxf(fmaxf(s4[i][0], s4[i][1]), fmaxf(s4[i][2], s4[i][3]));
#pragma unroll
      for (int mm = 1; mm < 16; mm <<= 1) r0 = fmaxf(r0, __shfl_xor(r0, mm));
      float rs = 0.0f;
#pragma unroll
      for (int j = 0; j < 4; ++j) {
        float pv = exp2f(s4[i][j] - r0);
        s4[i][j] = pv;
        rs += pv;
      }
#pragma unroll
      for (int mm = 1; mm < 16; mm <<= 1) rs += __shfl_xor(rs, mm);
      lrow[i] = rs;
    }
#pragma unroll
    for (int i = 0; i < 4; ++i)
      st4s(sQp, ty * 4 + i, tx, mk4(s4[i][0], s4[i][1], s4[i][2], s4[i][3]));
    float4 av[4];
#pragma unroll
    for (int i = 0; i < 4; ++i) av[i] = mk4(0.f, 0.f, 0.f, 0.f);
#pragma unroll 4
    for (int k4 = 0; k4 < 16; ++k4) {
      float4 v4[4];
#pragma unroll
      for (int kk = 0; kk < 4; ++kk) v4[kk] = ld4s(sVc, k4 * 4 + kk, tx);
#pragma unroll
      for (int i = 0; i < 4; ++i) {
        float4 p4 = ld4s(sQp, ty * 4 + i, k4);
        av[i].x += p4.x * v4[0].x; av[i].y += p4.x * v4[0].y;
        av[i].z += p4.x * v4[0].z; av[i].w += p4.x * v4[0].w;
        av[i].x += p4.y * v4[1].x; av[i].y += p4.y * v4[1].y;
        av[i].z += p4.y * v4[1].z; av[i].w += p4.y * v4[1].w;
        av[i].x += p4.z * v4[2].x; av[i].y += p4.z * v4[2].y;
        av[i].z += p4.z * v4[2].z; av[i].w += p4.z * v4[2].w;
        av[i].x += p4.w * v4[3].x; av[i].y += p4.w * v4[3].y;
        av[i].z += p4.w * v4[3].z; av[i].w += p4.w * v4[3].w;
      }
    }
#pragma unroll
    for (int i = 0; i < 4; ++i) {
      av[i].x /= lrow[i]; av[i].y /= lrow[i];
      av[i].z /= lrow[i]; av[i].w /= lrow[i];
    }
    if (mode == 0 && it == 0) {
#pragma unroll
      for (int i = 0; i < 4; ++i) {
        prev4[i] = av[i];
        int row = ty * 4 + i;
        float4 cq = ld4s(sX, row, tx);
        cq.x += av[i].x; cq.y += av[i].y; cq.z += av[i].z; cq.w += av[i].w;
        st4s(sX, row, tx, cq);
      }
    } else if (mode == 0) {  // it == 1
      float ds = 0.0f;
#pragma unroll
      for (int i = 0; i < 4; ++i) {
        int row = ty * 4 + i;
        ds += fabsf(av[i].x - prev4[i].x) + fabsf(av[i].y - prev4[i].y) +
              fabsf(av[i].z - prev4[i].z) + fabsf(av[i].w - prev4[i].w);
        float4 cq = ld4s(sX, row, tx);
        cq.x += av[i].x; cq.y += av[i].y; cq.z += av[i].z; cq.w += av[i].w;
        st4s(sX, row, tx, cq);
        size_t g = (bh1024 + t0 + row) * 64 + tx * 4;
        *(float4*)(curqg + g) = cq;
        *(float4*)(kcg + g) = ld4s(sKc, row, tx);
        *(float4*)(vcg + g) = ld4s(sVc, row, tx);
        size_t obase = ((size_t)b * 1024 + t0 + row) * 1024 + h * 64 + tx * 4;
        *(float4*)(outb + obase) = av[i];
      }
      __syncthreads();
      float* red = sKp;  // dead
      red[tid] = ds;
      __syncthreads();
      for (int s2 = 128; s2 > 0; s2 >>= 1) {
        if (tid < s2) red[tid] += red[tid + s2];
        __syncthreads();
      }
      if (tid == 0) diffp[bid] = red[0];
    } else {  // mode 2
#pragma unroll
      for (int i = 0; i < 4; ++i) {
        int row = ty * 4 + i;
        size_t obase = ((size_t)b * 1024 + t0 + row) * 1024 + h * 64 + tx * 4;
        *(float4*)(outb + obase) = av[i];
      }
    }
  }
}

// ---------------------------------------------------------------------------
// Final-focus attention v9 (unchanged from round 12 — best measured).
// ---------------------------------------------------------------------------
__global__ __launch_bounds__(TPB) void k_attn9(
    const float* __restrict__ qph, const float* __restrict__ kphT,
    const float* __restrict__ vbuf, float* __restrict__ curq,
    float* __restrict__ prevb, float* __restrict__ outb,
    float* __restrict__ diffp, const int* __restrict__ flags, int NQT,
    int nt, int mode) {
  constexpr int QT = 128;
  int bid0 = blockIdx.x;
  int bid = ((bid0 & 7) << 6) | (bid0 >> 3);  // XCD swizzle (512 = 8*64)
  int qt = bid % NQT;
  int bh = bid / NQT;
  int h = bh & 15, b = bh >> 4;
  if (mode == 2 && flags[0]) return;
  __shared__ float qTs[64][QT];
  __shared__ float kps[64 * QT];  // kT [d][k<64] then pT [k][q]
  __shared__ float vss[64 * 64];
  int tid = threadIdx.x;
  int tx = tid & 15, ty = tid >> 4;
  size_t bh1024 = (size_t)bh * 1024;
  size_t bh64 = (size_t)bh * 64;
  int q0 = qt * QT;
  // transpose Q into LDS (once per block)
#pragma unroll
  for (int i = 0; i < 8; ++i) {
    int f4id = i * 256 + tid;
    int row = f4id >> 4;
    int c4 = (f4id & 15) * 4;
    float4 v = *(const float4*)(qph + (bh1024 + q0 + row) * 64 + c4);
    qTs[c4 + 0][row] = v.x;
    qTs[c4 + 1][row] = v.y;
    qTs[c4 + 2][row] = v.z;
    qTs[c4 + 3][row] = v.w;
  }
  float m[8], l[8], acc[8][4];
#pragma unroll
  for (int i = 0; i < 8; ++i) {
    m[i] = -INFINITY; l[i] = 0.0f;
    acc[i][0] = acc[i][1] = acc[i][2] = acc[i][3] = 0.0f;
  }
  const float SCL = 0.18033688011112042f;  // log2(e)/8

  for (int kt = 0; kt < nt; ++kt) {
    int k0 = kt * 64;
#pragma unroll
    for (int i = 0; i < 4; ++i) {
      int f4id = i * 256 + tid;
      int rr = f4id >> 4;
      int c4 = (f4id & 15) * 4;
      *(float4*)&kps[rr * QT + c4] =
          *(const float4*)(kphT + (bh64 + rr) * 1024 + k0 + c4);
      *(float4*)&vss[rr * 64 + c4] =
          *(const float4*)(vbuf + (bh1024 + k0 + rr) * 64 + c4);
    }
    __syncthreads();
    float s[8][4];
#pragma unroll
    for (int i = 0; i < 8; ++i)
      s[i][0] = s[i][1] = s[i][2] = s[i][3] = 0.0f;
#pragma unroll 4
    for (int d = 0; d < 64; ++d) {
      float4 kv = *(const float4*)&kps[d * QT + tx * 4];
      float4 qa0 = *(const float4*)&qTs[d][ty * 8];
      float4 qa1 = *(const float4*)&qTs[d][ty * 8 + 4];
      float qv[8] = {qa0.x, qa0.y, qa0.z, qa0.w, qa1.x, qa1.y, qa1.z, qa1.w};
#pragma unroll
      for (int i = 0; i < 8; ++i) {
        s[i][0] += qv[i] * kv.x;
        s[i][1] += qv[i] * kv.y;
        s[i][2] += qv[i] * kv.z;
        s[i][3] += qv[i] * kv.w;
      }
    }
#pragma unroll
    for (int i = 0; i < 8; ++i) {
      s[i][0] *= SCL; s[i][1] *= SCL; s[i][2] *= SCL; s[i][3] *= SCL;
      float r0 = fmaxf(fmaxf(s[i][0], s[i][1]), fmaxf(s[i][2], s[i][3]));
#pragma unroll
      for (int mm = 1; mm < 16; mm <<= 1) r0 = fmaxf(r0, __shfl_xor(r0, mm));
      float mnew = fmaxf(m[i], r0);
      float sc = exp2f(m[i] - mnew);
      float rs = 0.0f;
#pragma unroll
      for (int j = 0; j < 4; ++j) {
        float pv = exp2f(s[i][j] - mnew);
        s[i][j] = pv;
        rs += pv;
      }
#pragma unroll
      for (int mm = 1; mm < 16; mm <<= 1) rs += __shfl_xor(rs, mm);
      l[i] = l[i] * sc + rs;
      m[i] = mnew;
      acc[i][0] *= sc; acc[i][1] *= sc; acc[i][2] *= sc; acc[i][3] *= sc;
    }
    __syncthreads();  // all S reads of kps done
#pragma unroll
    for (int jj = 0; jj < 4; ++jj) {
      *(float4*)&kps[(tx * 4 + jj) * QT + ty * 8] =
          mk4(s[0][jj], s[1][jj], s[2][jj], s[3][jj]);
      *(float4*)&kps[(tx * 4 + jj) * QT + ty * 8 + 4] =
          mk4(s[4][jj], s[5][jj], s[6][jj], s[7][jj]);
    }
    __syncthreads();
#pragma unroll 4
    for (int k = 0; k < 64; ++k) {
      float4 vv = *(const float4*)&vss[k * 64 + tx * 4];
      float4 pa0 = *(const float4*)&kps[k * QT + ty * 8];
      float4 pa1 = *(const float4*)&kps[k * QT + ty * 8 + 4];
      float pv[8] = {pa0.x, pa0.y, pa0.z, pa0.w, pa1.x, pa1.y, pa1.z, pa1.w};
#pragma unroll
      for (int i = 0; i < 8; ++i) {
        acc[i][0] += pv[i] * vv.x;
        acc[i][1] += pv[i] * vv.y;
        acc[i][2] += pv[i] * vv.z;
        acc[i][3] += pv[i] * vv.w;
      }
    }
    __syncthreads();
  }
  float ds = 0.0f;
#pragma unroll
  for (int i = 0; i < 8; ++i) {
    int t = q0 + ty * 8 + i;
    float4 att;
    att.x = acc[i][0] / l[i];
    att.y = acc[i][1] / l[i];
    att.z = acc[i][2] / l[i];
    att.w = acc[i][3] / l[i];
    size_t base = (bh1024 + t) * 64 + tx * 4;
    size_t obase = ((size_t)b * 1024 + t) * 1024 + h * 64 + tx * 4;
    if (mode == 0) {
      *(float4*)(prevb + base) = att;
      float4 cq = *(const float4*)(curq + base);
      cq.x += att.x; cq.y += att.y; cq.z += att.z; cq.w += att.w;
      *(float4*)(curq + base) = cq;
    } else if (mode == 1) {
      float4 pv = *(const float4*)(prevb + base);
      ds += fabsf(att.x - pv.x) + fabsf(att.y - pv.y) +
            fabsf(att.z - pv.z) + fabsf(att.w - pv.w);
      float4 cq = *(const float4*)(curq + base);
      cq.x += att.x; cq.y += att.y; cq.z += att.z; cq.w += att.w;
      *(float4*)(curq + base) = cq;
      *(float4*)(outb + obase) = att;
    } else {
      *(float4*)(outb + obase) = att;
    }
  }
  if (mode == 1) {
    __syncthreads();
    float* red = vss;  // dead
    red[tid] = ds;
    __syncthreads();
    for (int s2 = 128; s2 > 0; s2 >>= 1) {
      if (tid < s2) red[tid] += red[tid + s2];
      __syncthreads();
    }
    if (tid == 0) diffp[bid] = red[0];
  }
}

// Deterministic diff finalize.  flags[w] = mean over window < 0.5
__global__ __launch_bounds__(64) void k_finalize(const float* __restrict__ diffp,
                                                 int* __restrict__ flags,
                                                 int nwin, int nper,
                                                 float count) {
  int w = threadIdx.x;
  if (w < nwin) {
    float s = 0.0f;
    for (int i = 0; i < nper; ++i) s += diffp[w + i * nwin];
    flags[w] = (s / count < 0.5f) ? 1 : 0;
  }
}

// ---------------------------------------------------------------------------
extern "C" void kernel_launch(void* const* d_in, const int* in_sizes, int n_in,
                              void* d_out, int out_size, void* d_ws,
                              size_t ws_size, hipStream_t stream) {
  const float* x = (const float*)d_in[0];
  const float* xa = (const float*)d_in[1];
  const float* wqn = (const float*)d_in[2];
  const float* Wq = (const float*)d_in[3];
  const float* bq = (const float*)d_in[4];
  const float* wkvn = (const float*)d_in[5];
  const float* Wkv = (const float*)d_in[6];
  const float* bkv = (const float*)d_in[7];
  const float* wln = (const float*)d_in[8];
  const float* Wlq = (const float*)d_in[9];
  const float* blq = (const float*)d_in[10];
  const float* Wlk = (const float*)d_in[11];
  const float* blk = (const float*)d_in[12];
  const float* Wlv = (const float*)d_in[13];
  const float* blv = (const float*)d_in[14];
  const float* Wo = (const float*)d_in[15];
  const float* bo = (const float*)d_in[16];

  float* ws = (float*)d_ws;
  const size_t SLOT = (size_t)4 * 16 * 1024 * 64;  // 16 MiB
  float* xw = ws;
  float* xaw = ws + SLOT;
  float* Q = ws + 2 * SLOT;  // curq state
  float* K = ws + 3 * SLOT;
  float* V = ws + 4 * SLOT;
  float* kc = ws + 5 * SLOT;
  float* vc = ws + 6 * SLOT;
  float* prev = ws + 7 * SLOT;
  float* qph = ws + 8 * SLOT;
  float* kphT = ws + 9 * SLOT;
  float* misc = ws + 10 * SLOT;
  float* inv = misc;
  float* cosb = misc + 8192;
  float* sinb = cosb + 32768;
  float* diffp = sinb + 32768;
  int* flags = (int*)(diffp + 4096);

  k_tables<<<128, TPB, 0, stream>>>(cosb, sinb);

  for (int sl = 0; sl < 2; ++sl) {
    const float* Xin = sl ? xa : x;
    float* Xout = sl ? xaw : xw;
    k_rowinv<<<4096, TPB, 0, stream>>>(Xin, inv);
    k_gemm<64, 128><<<dim3(8, 64), TPB, 0, stream>>>(Xin, inv, wqn, Wq, bq, Q, nullptr, 1024, 1);
    k_gemm<128, 128><<<dim3(16, 32), TPB, 0, stream>>>(Xin, inv, wkvn, Wkv, bkv, K, V, 2048, 2);
    k_slide<<<1024, TPB, 0, stream>>>(Q, K, V, Q, kc, vc, Xout, diffp, nullptr,
                                      cosb, sinb, Wlq, blq, Wlk, blk, Wlv, blv,
                                      wln, 0);
    k_finalize<<<1, 64, 0, stream>>>(diffp, flags, 16, 64, 262144.0f);
    k_slide<<<1024, TPB, 0, stream>>>(Q, K, V, Q, kc, vc, Xout, diffp, flags,
                                      cosb, sinb, Wlq, blq, Wlk, blk, Wlv, blv,
                                      wln, 2);
  }

  // final focus: cq = ck = 1024
  k_rowinv<<<4096, TPB, 0, stream>>>(xw, inv);
  k_gemm<64, 128><<<dim3(8, 64), TPB, 0, stream>>>(xw, inv, wqn, Wq, bq, Q, nullptr, 1024, 1);
  k_rowinv<<<4096, TPB, 0, stream>>>(xaw, inv);
  k_gemm<128, 128><<<dim3(16, 32), TPB, 0, stream>>>(xaw, inv, wkvn, Wkv, bkv, K, V, 2048, 2);
  k_rope<<<8192, TPB, 0, stream>>>(Q, 1023, cosb, sinb);
  k_rope<<<8192, TPB, 0, stream>>>(K, 1023, cosb, sinb);
  float* fout = xw;  // reuse
  k_proj<<<4096, TPB, 0, stream>>>(Q, K, V, qph, kphT, Wlq, blq, Wlk, blk, Wlv, blv, wln, 1024, nullptr);
  k_attn9<<<512, TPB, 0, stream>>>(qph, kphT, V, Q, prev, fout, diffp, nullptr, 8, 16, 0);
  k_proj<<<4096, TPB, 0, stream>>>(Q, K, V, qph, kphT, Wlq, blq, Wlk, blk, Wlv, blv, wln, 1024, nullptr);
  k_attn9<<<512, TPB, 0, stream>>>(qph, kphT, V, Q, prev, fout, diffp, nullptr, 8, 16, 1);
  k_finalize<<<1, 64, 0, stream>>>(diffp, flags, 1, 512, 4194304.0f);
  k_proj<<<4096, TPB, 0, stream>>>(Q, K, V, qph, kphT, Wlq, blq, Wlk, blk, Wlv, blv, wln, 1024, flags);
  k_attn9<<<512, TPB, 0, stream>>>(qph, kphT, V, Q, prev, fout, diffp, flags, 8, 16, 2);

  k_gemm<64, 128><<<dim3(8, 64), TPB, 0, stream>>>(fout, nullptr, nullptr, Wo, bo, (float*)d_out, nullptr, 1024, 0);
}

// Round 14
// 2396.051 us; speedup vs baseline: 1.2249x; 1.2249x over previous
//
#include <hip/hip_runtime.h>
#include <math.h>

#define TPB 256

static __device__ __forceinline__ float4 mk4(float a, float b, float c, float d) {
  float4 r; r.x = a; r.y = b; r.z = c; r.w = d; return r;
}

// Swizzled LDS helpers for [64][64] f32 tiles: 16B chunk c of row r lives at
// chunk c ^ (r>>2).  Bank-conflict-free for row-broadcast + row-striped reads.
static __device__ __forceinline__ float4 ld4s(const float* buf, int row, int ch) {
  return *(const float4*)&buf[(row << 6) + (((ch ^ (row >> 2)) & 15) << 2)];
}
static __device__ __forceinline__ void st4s(float* buf, int row, int ch, float4 v) {
  *(float4*)&buf[(row << 6) + (((ch ^ (row >> 2)) & 15) << 2)] = v;
}

// ---------------------------------------------------------------------------
// RoPE cos/sin tables, replicating JAX f32 arithmetic exactly. (unchanged)
// ---------------------------------------------------------------------------
__global__ __launch_bounds__(TPB) void k_tables(float* __restrict__ cosb,
                                                float* __restrict__ sinb) {
  int gid = blockIdx.x * TPB + threadIdx.x;
  if (gid >= 1024 * 32) return;
  int t = gid >> 5, j = gid & 31;
  const double Ld = 1.3222192947339193;  // python math.log10(21.0)
  float Lf = (float)Ld;
  float mlog;
  if (j == 31) {
    mlog = Lf;
  } else {
    float stepf = (float)((double)j / 31.0);
    mlog = (float)((double)Lf * (double)stepf);
  }
  float p = (float)pow(10.0, (double)mlog);
  float mel = p - 1.0f;
  float t2 = (200.0f * mel) / 1000.0f;
  float freq = 163.63636363636363f * t2;
  float ang = (float)t * freq;
  double a = (double)ang;
  cosb[gid] = (float)cos(a);
  sinb[gid] = (float)sin(a);
}

// ---------------------------------------------------------------------------
// Per-row 1/rms over D=1024 (unchanged)
// ---------------------------------------------------------------------------
__global__ __launch_bounds__(TPB) void k_rowinv(const float* __restrict__ X,
                                                float* __restrict__ inv) {
  __shared__ float red[4];
  int row = blockIdx.x;
  int tid = threadIdx.x;
  float4 v = *(const float4*)(X + (size_t)row * 1024 + tid * 4);
  float ss = v.x * v.x + v.y * v.y + v.z * v.z + v.w * v.w;
#pragma unroll
  for (int m = 1; m < 64; m <<= 1) ss += __shfl_xor(ss, m);
  if ((tid & 63) == 0) red[tid >> 6] = ss;
  __syncthreads();
  if (tid == 0) {
    float s = ((red[0] + red[1]) + (red[2] + red[3]));
    float mm = s * (1.0f / 1024.0f) + 1.1920928955078125e-7f;
    inv[row] = (float)(1.0 / sqrt((double)mm));
  }
}

// ---------------------------------------------------------------------------
// Tiled f32 GEMM v3 (EXACT round-12 structure — 305us measured, VGPR 96;
// round-13's BK=32/dbuf variant demoted accumulators (VGPR 60) and halved
// VALUBusy, so it is reverted) + ONE addition: XCD-aware block swizzle.
// Flat dispatch id f is remapped so each XCD owns 1-2 W column-panels
// (SWZ=1: bx'=f&7; SWZ=2: bx'=2(f&7)+((f>>3)&1)) — W re-fetch drops ~8x.
// Pure index permutation: arithmetic bit-identical (absmax 1.373291e-4).
// ---------------------------------------------------------------------------
template <int BM, int BN, int SWZ>
__global__ __launch_bounds__(TPB) void k_gemm(
    const float* __restrict__ X, const float* __restrict__ inv,
    const float* __restrict__ wn, const float* __restrict__ W,
    const float* __restrict__ bias, float* __restrict__ o0,
    float* __restrict__ o1, int N, int mode) {
  constexpr int JW = BN / 64;    // col halves (1 or 2)
  constexpr int RH = BM / 64;    // row halves (1 or 2)
  constexpr int TPR = 256 / BM;  // threads staging one A row
  __shared__ float As[16][BM + 4];
  int tid = threadIdx.x;
  int bx, by;
  {
    int f = blockIdx.y * gridDim.x + blockIdx.x;
    if (SWZ == 1) {          // gridX == 8: one panel per XCD
      bx = f & 7;
      by = f >> 3;
    } else {                 // gridX == 16: two panels per XCD
      bx = 2 * (f & 7) + ((f >> 3) & 1);
      by = f >> 4;
    }
  }
  int tx = tid & 15, ty = tid >> 4;
  float c[4 * RH][4 * JW];
#pragma unroll
  for (int i = 0; i < 4 * RH; ++i)
#pragma unroll
    for (int j = 0; j < 4 * JW; ++j) c[i][j] = 0.0f;

  int arow = tid / TPR;
  int kqb[RH];
#pragma unroll
  for (int u = 0; u < RH; ++u) kqb[u] = ((tid % TPR) * RH + u) * 4;
  float sA = 1.0f;
  if (inv) sA = inv[by * BM + arow];
  const float* Xrow = X + (size_t)(by * BM + arow) * 1024;
  const float* Wb = W + bx * BN + tx * 4;

  float4 areg[RH];
#pragma unroll
  for (int u = 0; u < RH; ++u)
    areg[u] = *(const float4*)(Xrow + kqb[u]);

  for (int k0 = 0; k0 < 1024; k0 += 16) {
#pragma unroll
    for (int u = 0; u < RH; ++u) {
      int kq = kqb[u];
      float4 a4 = areg[u];
      if (wn) {
        float4 w4 = *(const float4*)(wn + k0 + kq);
        a4.x *= w4.x; a4.y *= w4.y; a4.z *= w4.z; a4.w *= w4.w;
      }
      a4.x *= sA; a4.y *= sA; a4.z *= sA; a4.w *= sA;
      As[kq + 0][arow] = a4.x;
      As[kq + 1][arow] = a4.y;
      As[kq + 2][arow] = a4.z;
      As[kq + 3][arow] = a4.w;
    }
    __syncthreads();
    if (k0 + 16 < 1024) {
#pragma unroll
      for (int u = 0; u < RH; ++u)
        areg[u] = *(const float4*)(Xrow + k0 + 16 + kqb[u]);
    }
#pragma unroll
    for (int kk = 0; kk < 16; ++kk) {
      float av[4 * RH];
      float4 a0 = *(const float4*)&As[kk][ty * 4];
      av[0] = a0.x; av[1] = a0.y; av[2] = a0.z; av[3] = a0.w;
      if (RH == 2) {
        float4 a1 = *(const float4*)&As[kk][64 + ty * 4];
        av[4] = a1.x; av[5] = a1.y; av[6] = a1.z; av[7] = a1.w;
      }
      const float* wrow = Wb + (size_t)(k0 + kk) * N;
      float4 b0 = *(const float4*)(wrow);
      float bv[4 * JW];
      bv[0] = b0.x; bv[1] = b0.y; bv[2] = b0.z; bv[3] = b0.w;
      if (JW == 2) {
        float4 b1 = *(const float4*)(wrow + 64);
        bv[4] = b1.x; bv[5] = b1.y; bv[6] = b1.z; bv[7] = b1.w;
      }
#pragma unroll
      for (int i = 0; i < 4 * RH; ++i)
#pragma unroll
        for (int j = 0; j < 4 * JW; ++j) c[i][j] += av[i] * bv[j];
    }
    __syncthreads();
  }

#pragma unroll
  for (int jh = 0; jh < JW; ++jh) {
    int colbase = bx * BN + jh * 64 + tx * 4;
    float4 bb = {0.f, 0.f, 0.f, 0.f};
    if (bias) bb = *(const float4*)(bias + colbase);
#pragma unroll
    for (int ih = 0; ih < RH; ++ih) {
#pragma unroll
      for (int i2 = 0; i2 < 4; ++i2) {
        int row = by * BM + ih * 64 + ty * 4 + i2;
        int ci = ih * 4 + i2;
        float4 o;
        o.x = c[ci][jh * 4 + 0] + bb.x;
        o.y = c[ci][jh * 4 + 1] + bb.y;
        o.z = c[ci][jh * 4 + 2] + bb.z;
        o.w = c[ci][jh * 4 + 3] + bb.w;
        if (mode == 0) {
          *(float4*)(o0 + (size_t)row * N + colbase) = o;
        } else {
          int b = row >> 10, t = row & 1023;
          float* dst = o0;
          int cc = colbase;
          if (mode == 2 && colbase >= 1024) { dst = o1; cc = colbase - 1024; }
          int ch = cc >> 6, d = cc & 63;
          *(float4*)(dst + ((size_t)((b * 16 + ch) * 1024 + t)) * 64 + d) = o;
        }
      }
    }
  }
}

// ---------------------------------------------------------------------------
// In-place RoPE (final focus only)
// ---------------------------------------------------------------------------
__global__ __launch_bounds__(TPB) void k_rope(float* __restrict__ A, int mask,
                                              const float* __restrict__ cosb,
                                              const float* __restrict__ sinb) {
  int gid = blockIdx.x * TPB + threadIdx.x;
  int j = gid & 31;
  int row = gid >> 5;
  int t = row & 1023;
  int aidx = ((t & mask) << 5) + j;
  float cc = cosb[aidx], sn = sinb[aidx];
  size_t base = (size_t)row * 64;
  float x1 = A[base + 2 * j], x2 = A[base + 2 * j + 1];
  A[base + 2 * j] = x1 * cc - x2 * sn;
  A[base + 2 * j + 1] = x1 * sn + x2 * cc;
}

// ---------------------------------------------------------------------------
// Projections for the FINAL focus (CQ=1024): qph (rms-normed, row-major),
// kc <- raw kp, kphT (rms-normed, TRANSPOSED [bh][d][t]), vc <- vp.
// ---------------------------------------------------------------------------
__global__ __launch_bounds__(TPB) void k_proj(
    const float* __restrict__ curq, float* __restrict__ kc,
    float* __restrict__ vc, float* __restrict__ qph, float* __restrict__ kphT,
    const float* __restrict__ Wlq, const float* __restrict__ blq,
    const float* __restrict__ Wlk, const float* __restrict__ blk,
    const float* __restrict__ Wlv, const float* __restrict__ blv,
    const float* __restrict__ wln, int CQ, const int* __restrict__ flags) {
  int RT = CQ >> 4;
  int bid = blockIdx.x;
  int rt = bid % RT;
  int rest = bid / RT;
  int h = rest & 15; rest >>= 4;
  int b = rest & 3;
  int win = rest >> 2;
  if (flags && flags[win]) return;
  __shared__ float qs[16][68], ksm[16][68], vsm[16][68];
  __shared__ float Wqs[4096], Wks[4096], Wvs[4096];
  int tid = threadIdx.x;
#pragma unroll
  for (int i = 0; i < 4; ++i) {
    int f4 = (i * 256 + tid) * 4;
    *(float4*)&Wqs[f4] = *(const float4*)(Wlq + f4);
    *(float4*)&Wks[f4] = *(const float4*)(Wlk + f4);
    *(float4*)&Wvs[f4] = *(const float4*)(Wlv + f4);
  }
  int lr = tid >> 4, c4 = (tid & 15) * 4;
  int bh = b * 16 + h;
  size_t rowbase = (size_t)bh * 1024 + (size_t)win * CQ + rt * 16;
  size_t g = (rowbase + lr) * 64 + c4;
  *(float4*)&qs[lr][c4] = *(const float4*)(curq + g);
  *(float4*)&ksm[lr][c4] = *(const float4*)(kc + g);
  *(float4*)&vsm[lr][c4] = *(const float4*)(vc + g);
  __syncthreads();
  int r = tid >> 4, cg = tid & 15;
  int tglob = win * CQ + rt * 16 + r;
  const float eps = 1.1920928955078125e-7f;
  float4 wl4 = *(const float4*)(wln + cg * 4);
  size_t orow = (rowbase + r) * 64 + cg * 4;
  float4 acc;
  float ssum, rms;
  // ---- Q
  acc = *(const float4*)(blq + cg * 4);
#pragma unroll 8
  for (int k = 0; k < 64; ++k) {
    float xv = qs[r][k];
    float4 w4 = *(const float4*)&Wqs[k * 64 + cg * 4];
    acc.x += xv * w4.x; acc.y += xv * w4.y;
    acc.z += xv * w4.z; acc.w += xv * w4.w;
  }
  ssum = acc.x * acc.x + acc.y * acc.y + acc.z * acc.z + acc.w * acc.w;
#pragma unroll
  for (int m = 1; m < 16; m <<= 1) ssum += __shfl_xor(ssum, m);
  rms = (float)(1.0 / sqrt((double)(ssum * 0.015625f + eps)));
  {
    float4 o;
    o.x = acc.x * rms * wl4.x; o.y = acc.y * rms * wl4.y;
    o.z = acc.z * rms * wl4.z; o.w = acc.w * rms * wl4.w;
    *(float4*)(qph + orow) = o;
  }
  // ---- K
  acc = *(const float4*)(blk + cg * 4);
#pragma unroll 8
  for (int k = 0; k < 64; ++k) {
    float xv = ksm[r][k];
    float4 w4 = *(const float4*)&Wks[k * 64 + cg * 4];
    acc.x += xv * w4.x; acc.y += xv * w4.y;
    acc.z += xv * w4.z; acc.w += xv * w4.w;
  }
  *(float4*)(kc + orow) = acc;  // raw kp -> next kc
  ssum = acc.x * acc.x + acc.y * acc.y + acc.z * acc.z + acc.w * acc.w;
#pragma unroll
  for (int m = 1; m < 16; m <<= 1) ssum += __shfl_xor(ssum, m);
  rms = (float)(1.0 / sqrt((double)(ssum * 0.015625f + eps)));
  {
    float no0 = acc.x * rms * wl4.x;
    float no1 = acc.y * rms * wl4.y;
    float no2 = acc.z * rms * wl4.z;
    float no3 = acc.w * rms * wl4.w;
    size_t tb = (size_t)bh * 64 + cg * 4;
    kphT[(tb + 0) * 1024 + tglob] = no0;
    kphT[(tb + 1) * 1024 + tglob] = no1;
    kphT[(tb + 2) * 1024 + tglob] = no2;
    kphT[(tb + 3) * 1024 + tglob] = no3;
  }
  // ---- V
  acc = *(const float4*)(blv + cg * 4);
#pragma unroll 8
  for (int k = 0; k < 64; ++k) {
    float xv = vsm[r][k];
    float4 w4 = *(const float4*)&Wvs[k * 64 + cg * 4];
    acc.x += xv * w4.x; acc.y += xv * w4.y;
    acc.z += xv * w4.z; acc.w += xv * w4.w;
  }
  *(float4*)(vc + orow) = acc;
}

// ---------------------------------------------------------------------------
// Per-thread 4-row proj for the fused slide kernel (unchanged)
// ---------------------------------------------------------------------------
static __device__ __forceinline__ void slide_proj_one(
    float* src, float* rawdst, float* ndst, const float* __restrict__ W,
    const float* __restrict__ bias, float4 wl4, int tx, int ty) {
  const float eps = 1.1920928955078125e-7f;
  float4 bb = *(const float4*)(bias + tx * 4);
  float4 acc[4];
#pragma unroll
  for (int i = 0; i < 4; ++i) acc[i] = bb;
#pragma unroll 2
  for (int k4 = 0; k4 < 16; ++k4) {
    const float* w = W + (k4 * 4) * 64 + tx * 4;
    float4 w0 = *(const float4*)(w);
    float4 w1 = *(const float4*)(w + 64);
    float4 w2 = *(const float4*)(w + 128);
    float4 w3 = *(const float4*)(w + 192);
#pragma unroll
    for (int i = 0; i < 4; ++i) {
      float4 a4 = ld4s(src, ty * 4 + i, k4);
      acc[i].x += a4.x * w0.x; acc[i].y += a4.x * w0.y;
      acc[i].z += a4.x * w0.z; acc[i].w += a4.x * w0.w;
      acc[i].x += a4.y * w1.x; acc[i].y += a4.y * w1.y;
      acc[i].z += a4.y * w1.z; acc[i].w += a4.y * w1.w;
      acc[i].x += a4.z * w2.x; acc[i].y += a4.z * w2.y;
      acc[i].z += a4.z * w2.z; acc[i].w += a4.z * w2.w;
      acc[i].x += a4.w * w3.x; acc[i].y += a4.w * w3.y;
      acc[i].z += a4.w * w3.z; acc[i].w += a4.w * w3.w;
    }
  }
#pragma unroll
  for (int i = 0; i < 4; ++i) {
    int row = ty * 4 + i;
    if (rawdst) st4s(rawdst, row, tx, acc[i]);
    if (ndst) {
      float ssum = acc[i].x * acc[i].x + acc[i].y * acc[i].y +
                   acc[i].z * acc[i].z + acc[i].w * acc[i].w;
#pragma unroll
      for (int mm = 1; mm < 16; mm <<= 1) ssum += __shfl_xor(ssum, mm);
      float rms = (float)(1.0 / sqrt((double)(ssum * 0.015625f + eps)));
      st4s(ndst, row, tx, mk4(acc[i].x * rms * wl4.x, acc[i].y * rms * wl4.y,
                              acc[i].z * rms * wl4.z, acc[i].w * rms * wl4.w));
    }
  }
}

// ---------------------------------------------------------------------------
// Fused slide-window focus (unchanged from round 5)
// ---------------------------------------------------------------------------
__global__ __launch_bounds__(TPB) void k_slide(
    const float* __restrict__ Qg, const float* __restrict__ Kg,
    const float* __restrict__ Vg, float* __restrict__ curqg,
    float* __restrict__ kcg, float* __restrict__ vcg, float* __restrict__ outb,
    float* __restrict__ diffp, const int* __restrict__ flags,
    const float* __restrict__ cosb, const float* __restrict__ sinb,
    const float* __restrict__ Wlq, const float* __restrict__ blq,
    const float* __restrict__ Wlk, const float* __restrict__ blk,
    const float* __restrict__ Wlv, const float* __restrict__ blv,
    const float* __restrict__ wln, int mode) {
  int bid = blockIdx.x;
  int win = bid & 15, bh = bid >> 4;
  int h = bh & 15, b = bh >> 4;
  if (mode == 2 && flags[win]) return;
  __shared__ float sX[4096], sKc[4096], sVc[4096], sQp[4096], sKp[4096];
  int tid = threadIdx.x;
  int tx = tid & 15, ty = tid >> 4;
  size_t bh1024 = (size_t)bh * 1024;
  int t0 = win * 64;
  const float SCL = 0.18033688011112042f;  // log2(e)/8

  if (mode == 0) {
    int sw = (win == 0) ? 0 : win * 64 - 4;
#pragma unroll
    for (int u = 0; u < 4; ++u) {
      int f4 = u * 256 + tid;
      int row = f4 >> 4, ch = f4 & 15;
      int aidx = (row << 5) + ch * 2;
      float c0 = cosb[aidx], s0 = sinb[aidx];
      float c1 = cosb[aidx + 1], s1 = sinb[aidx + 1];
      float4 q = *(const float4*)(Qg + (bh1024 + t0 + row) * 64 + ch * 4);
      st4s(sX, row, ch, mk4(q.x * c0 - q.y * s0, q.x * s0 + q.y * c0,
                            q.z * c1 - q.w * s1, q.z * s1 + q.w * c1));
      float4 k = *(const float4*)(Kg + (bh1024 + sw + row) * 64 + ch * 4);
      st4s(sKc, row, ch, mk4(k.x * c0 - k.y * s0, k.x * s0 + k.y * c0,
                             k.z * c1 - k.w * s1, k.z * s1 + k.w * c1));
      st4s(sVc, row, ch,
           *(const float4*)(Vg + (bh1024 + sw + row) * 64 + ch * 4));
    }
  } else {
#pragma unroll
    for (int u = 0; u < 4; ++u) {
      int f4 = u * 256 + tid;
      int row = f4 >> 4, ch = f4 & 15;
      size_t g = (bh1024 + t0 + row) * 64 + ch * 4;
      st4s(sX, row, ch, *(const float4*)(curqg + g));
      st4s(sKc, row, ch, *(const float4*)(kcg + g));
      st4s(sVc, row, ch, *(const float4*)(vcg + g));
    }
  }
  float4 wl4 = *(const float4*)(wln + tx * 4);
  float4 prev4[4];
  int niter = (mode == 0) ? 2 : 1;
  for (int it = 0; it < niter; ++it) {
    __syncthreads();
    slide_proj_one(sX, nullptr, sQp, Wlq, blq, wl4, tx, ty);
    slide_proj_one(sKc, sKc, sKp, Wlk, blk, wl4, tx, ty);
    slide_proj_one(sVc, sVc, nullptr, Wlv, blv, wl4, tx, ty);
    __syncthreads();
    float s4[4][4];
#pragma unroll
    for (int i = 0; i < 4; ++i)
      s4[i][0] = s4[i][1] = s4[i][2] = s4[i][3] = 0.0f;
#pragma unroll 4
    for (int d4 = 0; d4 < 16; ++d4) {
      float4 kv[4];
#pragma unroll
      for (int j = 0; j < 4; ++j) kv[j] = ld4s(sKp, tx * 4 + j, d4);
#pragma unroll
      for (int i = 0; i < 4; ++i) {
        float4 q4 = ld4s(sQp, ty * 4 + i, d4);
#pragma unroll
        for (int j = 0; j < 4; ++j) {
          s4[i][j] += q4.x * kv[j].x;
          s4[i][j] += q4.y * kv[j].y;
          s4[i][j] += q4.z * kv[j].z;
          s4[i][j] += q4.w * kv[j].w;
        }
      }
    }
    float lrow[4];
#pragma unroll
    for (int i = 0; i < 4; ++i) {
      s4[i][0] *= SCL; s4[i][1] *= SCL; s4[i][2] *= SCL; s4[i][3] *= SCL;
      float r0 = fmaxf(fmaxf(s4[i][0], s4[i][1]), fmaxf(s4[i][2], s4[i][3]));
#pragma unroll
      for (int mm = 1; mm < 16; mm <<= 1) r0 = fmaxf(r0, __shfl_xor(r0, mm));
      float rs = 0.0f;
#pragma unroll
      for (int j = 0; j < 4; ++j) {
        float pv = exp2f(s4[i][j] - r0);
        s4[i][j] = pv;
        rs += pv;
      }
#pragma unroll
      for (int mm = 1; mm < 16; mm <<= 1) rs += __shfl_xor(rs, mm);
      lrow[i] = rs;
    }
#pragma unroll
    for (int i = 0; i < 4; ++i)
      st4s(sQp, ty * 4 + i, tx, mk4(s4[i][0], s4[i][1], s4[i][2], s4[i][3]));
    float4 av[4];
#pragma unroll
    for (int i = 0; i < 4; ++i) av[i] = mk4(0.f, 0.f, 0.f, 0.f);
#pragma unroll 4
    for (int k4 = 0; k4 < 16; ++k4) {
      float4 v4[4];
#pragma unroll
      for (int kk = 0; kk < 4; ++kk) v4[kk] = ld4s(sVc, k4 * 4 + kk, tx);
#pragma unroll
      for (int i = 0; i < 4; ++i) {
        float4 p4 = ld4s(sQp, ty * 4 + i, k4);
        av[i].x += p4.x * v4[0].x; av[i].y += p4.x * v4[0].y;
        av[i].z += p4.x * v4[0].z; av[i].w += p4.x * v4[0].w;
        av[i].x += p4.y * v4[1].x; av[i].y += p4.y * v4[1].y;
        av[i].z += p4.y * v4[1].z; av[i].w += p4.y * v4[1].w;
        av[i].x += p4.z * v4[2].x; av[i].y += p4.z * v4[2].y;
        av[i].z += p4.z * v4[2].z; av[i].w += p4.z * v4[2].w;
        av[i].x += p4.w * v4[3].x; av[i].y += p4.w * v4[3].y;
        av[i].z += p4.w * v4[3].z; av[i].w += p4.w * v4[3].w;
      }
    }
#pragma unroll
    for (int i = 0; i < 4; ++i) {
      av[i].x /= lrow[i]; av[i].y /= lrow[i];
      av[i].z /= lrow[i]; av[i].w /= lrow[i];
    }
    if (mode == 0 && it == 0) {
#pragma unroll
      for (int i = 0; i < 4; ++i) {
        prev4[i] = av[i];
        int row = ty * 4 + i;
        float4 cq = ld4s(sX, row, tx);
        cq.x += av[i].x; cq.y += av[i].y; cq.z += av[i].z; cq.w += av[i].w;
        st4s(sX, row, tx, cq);
      }
    } else if (mode == 0) {  // it == 1
      float ds = 0.0f;
#pragma unroll
      for (int i = 0; i < 4; ++i) {
        int row = ty * 4 + i;
        ds += fabsf(av[i].x - prev4[i].x) + fabsf(av[i].y - prev4[i].y) +
              fabsf(av[i].z - prev4[i].z) + fabsf(av[i].w - prev4[i].w);
        float4 cq = ld4s(sX, row, tx);
        cq.x += av[i].x; cq.y += av[i].y; cq.z += av[i].z; cq.w += av[i].w;
        st4s(sX, row, tx, cq);
        size_t g = (bh1024 + t0 + row) * 64 + tx * 4;
        *(float4*)(curqg + g) = cq;
        *(float4*)(kcg + g) = ld4s(sKc, row, tx);
        *(float4*)(vcg + g) = ld4s(sVc, row, tx);
        size_t obase = ((size_t)b * 1024 + t0 + row) * 1024 + h * 64 + tx * 4;
        *(float4*)(outb + obase) = av[i];
      }
      __syncthreads();
      float* red = sKp;  // dead
      red[tid] = ds;
      __syncthreads();
      for (int s2 = 128; s2 > 0; s2 >>= 1) {
        if (tid < s2) red[tid] += red[tid + s2];
        __syncthreads();
      }
      if (tid == 0) diffp[bid] = red[0];
    } else {  // mode 2
#pragma unroll
      for (int i = 0; i < 4; ++i) {
        int row = ty * 4 + i;
        size_t obase = ((size_t)b * 1024 + t0 + row) * 1024 + h * 64 + tx * 4;
        *(float4*)(outb + obase) = av[i];
      }
    }
  }
}

// ---------------------------------------------------------------------------
// Final-focus attention v9 (unchanged from round 12 — best measured).
// ---------------------------------------------------------------------------
__global__ __launch_bounds__(TPB) void k_attn9(
    const float* __restrict__ qph, const float* __restrict__ kphT,
    const float* __restrict__ vbuf, float* __restrict__ curq,
    float* __restrict__ prevb, float* __restrict__ outb,
    float* __restrict__ diffp, const int* __restrict__ flags, int NQT,
    int nt, int mode) {
  constexpr int QT = 128;
  int bid0 = blockIdx.x;
  int bid = ((bid0 & 7) << 6) | (bid0 >> 3);  // XCD swizzle (512 = 8*64)
  int qt = bid % NQT;
  int bh = bid / NQT;
  int h = bh & 15, b = bh >> 4;
  if (mode == 2 && flags[0]) return;
  __shared__ float qTs[64][QT];
  __shared__ float kps[64 * QT];  // kT [d][k<64] then pT [k][q]
  __shared__ float vss[64 * 64];
  int tid = threadIdx.x;
  int tx = tid & 15, ty = tid >> 4;
  size_t bh1024 = (size_t)bh * 1024;
  size_t bh64 = (size_t)bh * 64;
  int q0 = qt * QT;
  // transpose Q into LDS (once per block)
#pragma unroll
  for (int i = 0; i < 8; ++i) {
    int f4id = i * 256 + tid;
    int row = f4id >> 4;
    int c4 = (f4id & 15) * 4;
    float4 v = *(const float4*)(qph + (bh1024 + q0 + row) * 64 + c4);
    qTs[c4 + 0][row] = v.x;
    qTs[c4 + 1][row] = v.y;
    qTs[c4 + 2][row] = v.z;
    qTs[c4 + 3][row] = v.w;
  }
  float m[8], l[8], acc[8][4];
#pragma unroll
  for (int i = 0; i < 8; ++i) {
    m[i] = -INFINITY; l[i] = 0.0f;
    acc[i][0] = acc[i][1] = acc[i][2] = acc[i][3] = 0.0f;
  }
  const float SCL = 0.18033688011112042f;  // log2(e)/8

  for (int kt = 0; kt < nt; ++kt) {
    int k0 = kt * 64;
#pragma unroll
    for (int i = 0; i < 4; ++i) {
      int f4id = i * 256 + tid;
      int rr = f4id >> 4;
      int c4 = (f4id & 15) * 4;
      *(float4*)&kps[rr * QT + c4] =
          *(const float4*)(kphT + (bh64 + rr) * 1024 + k0 + c4);
      *(float4*)&vss[rr * 64 + c4] =
          *(const float4*)(vbuf + (bh1024 + k0 + rr) * 64 + c4);
    }
    __syncthreads();
    float s[8][4];
#pragma unroll
    for (int i = 0; i < 8; ++i)
      s[i][0] = s[i][1] = s[i][2] = s[i][3] = 0.0f;
#pragma unroll 4
    for (int d = 0; d < 64; ++d) {
      float4 kv = *(const float4*)&kps[d * QT + tx * 4];
      float4 qa0 = *(const float4*)&qTs[d][ty * 8];
      float4 qa1 = *(const float4*)&qTs[d][ty * 8 + 4];
      float qv[8] = {qa0.x, qa0.y, qa0.z, qa0.w, qa1.x, qa1.y, qa1.z, qa1.w};
#pragma unroll
      for (int i = 0; i < 8; ++i) {
        s[i][0] += qv[i] * kv.x;
        s[i][1] += qv[i] * kv.y;
        s[i][2] += qv[i] * kv.z;
        s[i][3] += qv[i] * kv.w;
      }
    }
#pragma unroll
    for (int i = 0; i < 8; ++i) {
      s[i][0] *= SCL; s[i][1] *= SCL; s[i][2] *= SCL; s[i][3] *= SCL;
      float r0 = fmaxf(fmaxf(s[i][0], s[i][1]), fmaxf(s[i][2], s[i][3]));
#pragma unroll
      for (int mm = 1; mm < 16; mm <<= 1) r0 = fmaxf(r0, __shfl_xor(r0, mm));
      float mnew = fmaxf(m[i], r0);
      float sc = exp2f(m[i] - mnew);
      float rs = 0.0f;
#pragma unroll
      for (int j = 0; j < 4; ++j) {
        float pv = exp2f(s[i][j] - mnew);
        s[i][j] = pv;
        rs += pv;
      }
#pragma unroll
      for (int mm = 1; mm < 16; mm <<= 1) rs += __shfl_xor(rs, mm);
      l[i] = l[i] * sc + rs;
      m[i] = mnew;
      acc[i][0] *= sc; acc[i][1] *= sc; acc[i][2] *= sc; acc[i][3] *= sc;
    }
    __syncthreads();  // all S reads of kps done
#pragma unroll
    for (int jj = 0; jj < 4; ++jj) {
      *(float4*)&kps[(tx * 4 + jj) * QT + ty * 8] =
          mk4(s[0][jj], s[1][jj], s[2][jj], s[3][jj]);
      *(float4*)&kps[(tx * 4 + jj) * QT + ty * 8 + 4] =
          mk4(s[4][jj], s[5][jj], s[6][jj], s[7][jj]);
    }
    __syncthreads();
#pragma unroll 4
    for (int k = 0; k < 64; ++k) {
      float4 vv = *(const float4*)&vss[k * 64 + tx * 4];
      float4 pa0 = *(const float4*)&kps[k * QT + ty * 8];
      float4 pa1 = *(const float4*)&kps[k * QT + ty * 8 + 4];
      float pv[8] = {pa0.x, pa0.y, pa0.z, pa0.w, pa1.x, pa1.y, pa1.z, pa1.w};
#pragma unroll
      for (int i = 0; i < 8; ++i) {
        acc[i][0] += pv[i] * vv.x;
        acc[i][1] += pv[i] * vv.y;
        acc[i][2] += pv[i] * vv.z;
        acc[i][3] += pv[i] * vv.w;
      }
    }
    __syncthreads();
  }
  float ds = 0.0f;
#pragma unroll
  for (int i = 0; i < 8; ++i) {
    int t = q0 + ty * 8 + i;
    float4 att;
    att.x = acc[i][0] / l[i];
    att.y = acc[i][1] / l[i];
    att.z = acc[i][2] / l[i];
    att.w = acc[i][3] / l[i];
    size_t base = (bh1024 + t) * 64 + tx * 4;
    size_t obase = ((size_t)b * 1024 + t) * 1024 + h * 64 + tx * 4;
    if (mode == 0) {
      *(float4*)(prevb + base) = att;
      float4 cq = *(const float4*)(curq + base);
      cq.x += att.x; cq.y += att.y; cq.z += att.z; cq.w += att.w;
      *(float4*)(curq + base) = cq;
    } else if (mode == 1) {
      float4 pv = *(const float4*)(prevb + base);
      ds += fabsf(att.x - pv.x) + fabsf(att.y - pv.y) +
            fabsf(att.z - pv.z) + fabsf(att.w - pv.w);
      float4 cq = *(const float4*)(curq + base);
      cq.x += att.x; cq.y += att.y; cq.z += att.z; cq.w += att.w;
      *(float4*)(curq + base) = cq;
      *(float4*)(outb + obase) = att;
    } else {
      *(float4*)(outb + obase) = att;
    }
  }
  if (mode == 1) {
    __syncthreads();
    float* red = vss;  // dead
    red[tid] = ds;
    __syncthreads();
    for (int s2 = 128; s2 > 0; s2 >>= 1) {
      if (tid < s2) red[tid] += red[tid + s2];
      __syncthreads();
    }
    if (tid == 0) diffp[bid] = red[0];
  }
}

// Deterministic diff finalize.  flags[w] = mean over window < 0.5
__global__ __launch_bounds__(64) void k_finalize(const float* __restrict__ diffp,
                                                 int* __restrict__ flags,
                                                 int nwin, int nper,
                                                 float count) {
  int w = threadIdx.x;
  if (w < nwin) {
    float s = 0.0f;
    for (int i = 0; i < nper; ++i) s += diffp[w + i * nwin];
    flags[w] = (s / count < 0.5f) ? 1 : 0;
  }
}

// ---------------------------------------------------------------------------
extern "C" void kernel_launch(void* const* d_in, const int* in_sizes, int n_in,
                              void* d_out, int out_size, void* d_ws,
                              size_t ws_size, hipStream_t stream) {
  const float* x = (const float*)d_in[0];
  const float* xa = (const float*)d_in[1];
  const float* wqn = (const float*)d_in[2];
  const float* Wq = (const float*)d_in[3];
  const float* bq = (const float*)d_in[4];
  const float* wkvn = (const float*)d_in[5];
  const float* Wkv = (const float*)d_in[6];
  const float* bkv = (const float*)d_in[7];
  const float* wln = (const float*)d_in[8];
  const float* Wlq = (const float*)d_in[9];
  const float* blq = (const float*)d_in[10];
  const float* Wlk = (const float*)d_in[11];
  const float* blk = (const float*)d_in[12];
  const float* Wlv = (const float*)d_in[13];
  const float* blv = (const float*)d_in[14];
  const float* Wo = (const float*)d_in[15];
  const float* bo = (const float*)d_in[16];

  float* ws = (float*)d_ws;
  const size_t SLOT = (size_t)4 * 16 * 1024 * 64;  // 16 MiB
  float* xw = ws;
  float* xaw = ws + SLOT;
  float* Q = ws + 2 * SLOT;  // curq state
  float* K = ws + 3 * SLOT;
  float* V = ws + 4 * SLOT;
  float* kc = ws + 5 * SLOT;
  float* vc = ws + 6 * SLOT;
  float* prev = ws + 7 * SLOT;
  float* qph = ws + 8 * SLOT;
  float* kphT = ws + 9 * SLOT;
  float* misc = ws + 10 * SLOT;
  float* inv = misc;
  float* cosb = misc + 8192;
  float* sinb = cosb + 32768;
  float* diffp = sinb + 32768;
  int* flags = (int*)(diffp + 4096);

  k_tables<<<128, TPB, 0, stream>>>(cosb, sinb);

  for (int sl = 0; sl < 2; ++sl) {
    const float* Xin = sl ? xa : x;
    float* Xout = sl ? xaw : xw;
    k_rowinv<<<4096, TPB, 0, stream>>>(Xin, inv);
    k_gemm<64, 128, 1><<<dim3(8, 64), TPB, 0, stream>>>(Xin, inv, wqn, Wq, bq, Q, nullptr, 1024, 1);
    k_gemm<128, 128, 2><<<dim3(16, 32), TPB, 0, stream>>>(Xin, inv, wkvn, Wkv, bkv, K, V, 2048, 2);
    k_slide<<<1024, TPB, 0, stream>>>(Q, K, V, Q, kc, vc, Xout, diffp, nullptr,
                                      cosb, sinb, Wlq, blq, Wlk, blk, Wlv, blv,
                                      wln, 0);
    k_finalize<<<1, 64, 0, stream>>>(diffp, flags, 16, 64, 262144.0f);
    k_slide<<<1024, TPB, 0, stream>>>(Q, K, V, Q, kc, vc, Xout, diffp, flags,
                                      cosb, sinb, Wlq, blq, Wlk, blk, Wlv, blv,
                                      wln, 2);
  }

  // final focus: cq = ck = 1024
  k_rowinv<<<4096, TPB, 0, stream>>>(xw, inv);
  k_gemm<64, 128, 1><<<dim3(8, 64), TPB, 0, stream>>>(xw, inv, wqn, Wq, bq, Q, nullptr, 1024, 1);
  k_rowinv<<<4096, TPB, 0, stream>>>(xaw, inv);
  k_gemm<128, 128, 2><<<dim3(16, 32), TPB, 0, stream>>>(xaw, inv, wkvn, Wkv, bkv, K, V, 2048, 2);
  k_rope<<<8192, TPB, 0, stream>>>(Q, 1023, cosb, sinb);
  k_rope<<<8192, TPB, 0, stream>>>(K, 1023, cosb, sinb);
  float* fout = xw;  // reuse
  k_proj<<<4096, TPB, 0, stream>>>(Q, K, V, qph, kphT, Wlq, blq, Wlk, blk, Wlv, blv, wln, 1024, nullptr);
  k_attn9<<<512, TPB, 0, stream>>>(qph, kphT, V, Q, prev, fout, diffp, nullptr, 8, 16, 0);
  k_proj<<<4096, TPB, 0, stream>>>(Q, K, V, qph, kphT, Wlq, blq, Wlk, blk, Wlv, blv, wln, 1024, nullptr);
  k_attn9<<<512, TPB, 0, stream>>>(qph, kphT, V, Q, prev, fout, diffp, nullptr, 8, 16, 1);
  k_finalize<<<1, 64, 0, stream>>>(diffp, flags, 1, 512, 4194304.0f);
  k_proj<<<4096, TPB, 0, stream>>>(Q, K, V, qph, kphT, Wlq, blq, Wlk, blk, Wlv, blv, wln, 1024, flags);
  k_attn9<<<512, TPB, 0, stream>>>(qph, kphT, V, Q, prev, fout, diffp, flags, 8, 16, 2);

  k_gemm<64, 128, 1><<<dim3(8, 64), TPB, 0, stream>>>(fout, nullptr, nullptr, Wo, bo, (float*)d_out, nullptr, 1024, 0);
}